// Round 1
// baseline (9202.145 us; speedup 1.0000x reference)
//
#include <hip/hip_runtime.h>
#include <cstdint>
#include <cstddef>

typedef unsigned long long ull;

#define N_PTS  32768
#define NP1    2048
#define NSAMP1 32
#define NP2    512
#define NSAMP2 64

// ---------------- prep: xyz = points - [x,y,0], SoA ----------------
__global__ __launch_bounds__(256) void k_prep(const float* __restrict__ pts,
                                              const float* __restrict__ prop,
                                              float* __restrict__ xx,
                                              float* __restrict__ xy,
                                              float* __restrict__ xz) {
  int t = blockIdx.x * 256 + threadIdx.x;
  if (t >= N_PTS) return;
  float x = prop[0], y = prop[1];
  xx[t] = __fsub_rn(pts[3 * t + 0], x);
  xy[t] = __fsub_rn(pts[3 * t + 1], y);
  xz[t] = pts[3 * t + 2];
}

// ---------------- FPS1: 2048 of 32768, single persistent block ----------------
#define F1T 512
#define F1P 64
#define F1R 36                // z-coords kept in regs for s < F1R
#define F1L (F1P - F1R)       // 28 z-coord slices in LDS (28*512*4 = 56 KB)

__global__ __launch_bounds__(F1T) void k_fps1(const float* __restrict__ xx,
                                              const float* __restrict__ xy,
                                              const float* __restrict__ xz,
                                              float* __restrict__ ox,
                                              float* __restrict__ oy,
                                              float* __restrict__ oz) {
  __shared__ float pzl[F1L * F1T];
  __shared__ ull wkeys[F1T / 64];
  __shared__ int bshare;
  int tid = threadIdx.x;
  float px[F1P], py[F1P], pzr[F1R], d[F1P];
#pragma unroll
  for (int s = 0; s < F1P; ++s) {
    int i = s * F1T + tid;                    // point-major: coalesced, LDS conflict-free
    px[s] = xx[i];
    py[s] = xy[i];
    float z = xz[i];
    if (s < F1R) pzr[s] = z;
    else pzl[(s - F1R) * F1T + tid] = z;
    d[s] = 1e10f;
  }
  if (tid == 0) bshare = 0;
  __syncthreads();
  for (int it = 0; it < NP1; ++it) {
    int f = __builtin_amdgcn_readfirstlane(bshare);
    float cx = xx[f], cy = xy[f], cz = xz[f];
    if (tid == 0) { ox[it] = cx; oy[it] = cy; oz[it] = cz; }
    float bestv = -1.0f;
    int besti = 0;
#pragma unroll
    for (int s = 0; s < F1P; ++s) {
      float z = (s < F1R) ? pzr[s] : pzl[(s - F1R) * F1T + tid];
      // exact reference arithmetic: no fma, (dx^2 + dy^2) + dz^2
      float dx = __fsub_rn(px[s], cx);
      float dy = __fsub_rn(py[s], cy);
      float dz = __fsub_rn(z, cz);
      float d2 = __fadd_rn(__fadd_rn(__fmul_rn(dx, dx), __fmul_rn(dy, dy)), __fmul_rn(dz, dz));
      float dn = fminf(d[s], d2);
      d[s] = dn;
      bool gt = dn > bestv;                   // strict > keeps smallest index on ties
      bestv = gt ? dn : bestv;
      besti = gt ? (s * F1T + tid) : besti;
    }
    // pack: max value wins; on equal value, smaller index wins (dists >= 0 so bits monotone)
    ull key = ((ull)__float_as_uint(bestv) << 32) | (unsigned)(~besti);
#pragma unroll
    for (int m = 1; m < 64; m <<= 1) {
      ull o = __shfl_xor(key, m, 64);
      key = (o > key) ? o : key;
    }
    if ((tid & 63) == 0) wkeys[tid >> 6] = key;
    __syncthreads();
    if (tid < 64) {
      ull k2 = (tid < (F1T / 64)) ? wkeys[tid] : 0ull;
#pragma unroll
      for (int m = 1; m < (F1T / 64); m <<= 1) {
        ull o = __shfl_xor(k2, m, 64);
        k2 = (o > k2) ? o : k2;
      }
      if (tid == 0) bshare = (int)(~(unsigned)k2);
    }
    __syncthreads();
  }
}

// ---------------- FPS2: 512 of 2048 ----------------
#define F2T 1024
__global__ __launch_bounds__(F2T) void k_fps2(const float* __restrict__ x1x,
                                              const float* __restrict__ x1y,
                                              const float* __restrict__ x1z,
                                              float* __restrict__ ox,
                                              float* __restrict__ oy,
                                              float* __restrict__ oz) {
  __shared__ ull wkeys[F2T / 64];
  __shared__ int bshare;
  int tid = threadIdx.x;
  float px[2], py[2], pz[2], d[2];
#pragma unroll
  for (int s = 0; s < 2; ++s) {
    int i = s * F2T + tid;
    px[s] = x1x[i]; py[s] = x1y[i]; pz[s] = x1z[i];
    d[s] = 1e10f;
  }
  if (tid == 0) bshare = 0;
  __syncthreads();
  for (int it = 0; it < NP2; ++it) {
    int f = __builtin_amdgcn_readfirstlane(bshare);
    float cx = x1x[f], cy = x1y[f], cz = x1z[f];
    if (tid == 0) { ox[it] = cx; oy[it] = cy; oz[it] = cz; }
    float bestv = -1.0f;
    int besti = 0;
#pragma unroll
    for (int s = 0; s < 2; ++s) {
      float dx = __fsub_rn(px[s], cx);
      float dy = __fsub_rn(py[s], cy);
      float dz = __fsub_rn(pz[s], cz);
      float d2 = __fadd_rn(__fadd_rn(__fmul_rn(dx, dx), __fmul_rn(dy, dy)), __fmul_rn(dz, dz));
      float dn = fminf(d[s], d2);
      d[s] = dn;
      bool gt = dn > bestv;
      bestv = gt ? dn : bestv;
      besti = gt ? (s * F2T + tid) : besti;
    }
    ull key = ((ull)__float_as_uint(bestv) << 32) | (unsigned)(~besti);
#pragma unroll
    for (int m = 1; m < 64; m <<= 1) {
      ull o = __shfl_xor(key, m, 64);
      key = (o > key) ? o : key;
    }
    if ((tid & 63) == 0) wkeys[tid >> 6] = key;
    __syncthreads();
    if (tid < 64) {
      ull k2 = (tid < (F2T / 64)) ? wkeys[tid] : 0ull;
#pragma unroll
      for (int m = 1; m < (F2T / 64); m <<= 1) {
        ull o = __shfl_xor(k2, m, 64);
        k2 = (o > k2) ? o : k2;
      }
      if (tid == 0) bshare = (int)(~(unsigned)k2);
    }
    __syncthreads();
  }
}

// ---------------- ball query: first ns indices (ascending) within r2, pad with first ----------------
__global__ void k_ballq(const float* __restrict__ px, const float* __restrict__ py,
                        const float* __restrict__ pz, int n,
                        const float* __restrict__ qx, const float* __restrict__ qy,
                        const float* __restrict__ qz, int S,
                        float r2, int ns, int* __restrict__ out) {
  int w = (blockIdx.x * (int)blockDim.x + threadIdx.x) >> 6;  // one wave per query
  int lane = threadIdx.x & 63;
  if (w >= S) return;
  float cx = qx[w], cy = qy[w], cz = qz[w];
  int found = 0, first = 0;
  bool havefirst = false;
  for (int base = 0; base < n && found < ns; base += 64) {
    int i = base + lane;
    float dx = __fsub_rn(px[i], cx);
    float dy = __fsub_rn(py[i], cy);
    float dz = __fsub_rn(pz[i], cz);
    float d2 = __fadd_rn(__fadd_rn(__fmul_rn(dx, dx), __fmul_rn(dy, dy)), __fmul_rn(dz, dz));
    bool isin = d2 <= r2;
    ull m = __ballot(isin);
    if (!havefirst && m != 0ull) { first = base + __builtin_ctzll(m); havefirst = true; }
    if (isin) {
      int r = (int)__popcll(m & ((1ull << lane) - 1ull));
      int slot = found + r;
      if (slot < ns) out[w * ns + slot] = i;
    }
    found += (int)__popcll(m);
  }
  for (int s2 = found + lane; s2 < ns; s2 += 64) out[w * ns + s2] = first;
}

// ---------------- gather SA1 input rows (15 ch) ----------------
__global__ __launch_bounds__(256) void k_gather1(const float* __restrict__ pts,
                                                 const float* __restrict__ prop,
                                                 const float* __restrict__ xx,
                                                 const float* __restrict__ xy,
                                                 const float* __restrict__ xz,
                                                 const float* __restrict__ x1x,
                                                 const float* __restrict__ x1y,
                                                 const float* __restrict__ x1z,
                                                 const int* __restrict__ gidx,
                                                 float* __restrict__ X, int rbase) {
  int rl = blockIdx.x * 256 + threadIdx.x;
  if (rl >= 8192) return;
  int r = rbase + rl;
  int s = r >> 5;
  int g = gidx[r];
  float x = prop[0], y = prop[1], wz = prop[3];
  float w2 = wz * 0.5f;  // == w/2 exactly
  float oxp = __fadd_rn(x, w2), oxm = __fsub_rn(x, w2);
  float oyp = __fadd_rn(y, w2), oym = __fsub_rn(y, w2);
  float gx = xx[g], gy = xy[g], gz = xz[g];
  float pxv = pts[3 * g + 0], pyv = pts[3 * g + 1];
  float* o = X + (size_t)rl * 15;
  o[0] = __fsub_rn(gx, x1x[s]);
  o[1] = __fsub_rn(gy, x1y[s]);
  o[2] = __fsub_rn(gz, x1z[s]);
  o[3] = __fsub_rn(pxv, oxp);  o[4]  = gy;                    o[5]  = gz;
  o[6] = __fsub_rn(pxv, oxm);  o[7]  = gy;                    o[8]  = gz;
  o[9] = gx;                   o[10] = __fsub_rn(pyv, oyp);   o[11] = gz;
  o[12] = gx;                  o[13] = __fsub_rn(pyv, oym);   o[14] = gz;
}

// ---------------- gather SA2 input rows (131 ch), element-parallel ----------------
__global__ __launch_bounds__(256) void k_gather2(const float* __restrict__ x1x,
                                                 const float* __restrict__ x1y,
                                                 const float* __restrict__ x1z,
                                                 const float* __restrict__ x2x,
                                                 const float* __restrict__ x2y,
                                                 const float* __restrict__ x2z,
                                                 const int* __restrict__ gidx,
                                                 const float* __restrict__ f1,
                                                 float* __restrict__ X, int rbase) {
  int e = blockIdx.x * 256 + threadIdx.x;
  if (e >= 8192 * 131) return;
  int rl = e / 131, c = e % 131;
  int r = rbase + rl;
  int s = r >> 6;
  int g = gidx[r];
  float v;
  if (c == 0)      v = __fsub_rn(x1x[g], x2x[s]);
  else if (c == 1) v = __fsub_rn(x1y[g], x2y[s]);
  else if (c == 2) v = __fsub_rn(x1z[g], x2z[s]);
  else             v = f1[(size_t)g * 128 + (c - 3)];
  X[e] = v;
}

// ---------------- gather SA3 input rows (259 ch) ----------------
__global__ __launch_bounds__(256) void k_gather3(const float* __restrict__ x2x,
                                                 const float* __restrict__ x2y,
                                                 const float* __restrict__ x2z,
                                                 const float* __restrict__ f2,
                                                 float* __restrict__ X) {
  int e = blockIdx.x * 256 + threadIdx.x;
  if (e >= 512 * 259) return;
  int rl = e / 259, c = e % 259;
  float v;
  if (c == 0)      v = x2x[rl];
  else if (c == 1) v = x2y[rl];
  else if (c == 2) v = x2z[rl];
  else             v = f2[(size_t)rl * 256 + (c - 3)];
  X[e] = v;
}

// ---------------- relu GEMM: C[m][n] = relu(bias[n] + sum_k A[m,k]*W[n,k]) ----------------
// 64x64 tile, 256 threads, 4x4 per thread, transposed LDS staging for b128 reads
__global__ __launch_bounds__(256) void k_gemm(const float* __restrict__ A,
                                              const float* __restrict__ W,
                                              const float* __restrict__ bias,
                                              float* __restrict__ C,
                                              int M, int N, int K) {
  __shared__ __align__(16) float As[16][68];
  __shared__ __align__(16) float Bs[16][68];
  int tid = threadIdx.x;
  int bn = blockIdx.x * 64, bm = blockIdx.y * 64;
  int tx = tid & 15, ty = tid >> 4;
  float acc[4][4] = {{0.f, 0.f, 0.f, 0.f}, {0.f, 0.f, 0.f, 0.f},
                     {0.f, 0.f, 0.f, 0.f}, {0.f, 0.f, 0.f, 0.f}};
  for (int k0 = 0; k0 < K; k0 += 16) {
#pragma unroll
    for (int e = 0; e < 4; ++e) {
      int flat = tid + e * 256;
      int rr = flat >> 4, cc = flat & 15;
      As[cc][rr] = (k0 + cc < K) ? A[(size_t)(bm + rr) * K + (k0 + cc)] : 0.0f;
      Bs[cc][rr] = (k0 + cc < K) ? W[(size_t)(bn + rr) * K + (k0 + cc)] : 0.0f;
    }
    __syncthreads();
#pragma unroll
    for (int kk = 0; kk < 16; ++kk) {
      const float4 a = *(const float4*)&As[kk][ty * 4];
      const float4 b = *(const float4*)&Bs[kk][tx * 4];
      float av[4] = {a.x, a.y, a.z, a.w};
      float bb[4] = {b.x, b.y, b.z, b.w};
#pragma unroll
      for (int i = 0; i < 4; ++i)
#pragma unroll
        for (int j = 0; j < 4; ++j)
          acc[i][j] = fmaf(av[i], bb[j], acc[i][j]);
    }
    __syncthreads();
  }
#pragma unroll
  for (int i = 0; i < 4; ++i) {
    int m = bm + ty * 4 + i;
    float4 o;
    o.x = fmaxf(acc[i][0] + bias[bn + tx * 4 + 0], 0.0f);
    o.y = fmaxf(acc[i][1] + bias[bn + tx * 4 + 1], 0.0f);
    o.z = fmaxf(acc[i][2] + bias[bn + tx * 4 + 2], 0.0f);
    o.w = fmaxf(acc[i][3] + bias[bn + tx * 4 + 3], 0.0f);
    *(float4*)&C[(size_t)m * N + bn + tx * 4] = o;
  }
}

// ---------------- maxpool over Ks consecutive rows ----------------
__global__ __launch_bounds__(256) void k_maxpool(const float* __restrict__ H,
                                                 float* __restrict__ F,
                                                 int S, int Ks, int Nch, int sbase) {
  int t = blockIdx.x * 256 + threadIdx.x;
  if (t >= S * Nch) return;
  int sl = t / Nch, n = t % Nch;
  const float* p = H + (size_t)sl * Ks * Nch + n;
  float m = p[0];
  for (int k = 1; k < Ks; ++k) m = fmaxf(m, p[(size_t)k * Nch]);
  F[(size_t)(sbase + sl) * Nch + n] = m;
}

// ---------------- host ----------------
extern "C" void kernel_launch(void* const* d_in, const int* in_sizes, int n_in,
                              void* d_out, int out_size, void* d_ws, size_t ws_size,
                              hipStream_t stream) {
  (void)n_in; (void)out_size; (void)ws_size;
  const float* pts = (const float*)d_in[0];
  const float* prop = (const float*)d_in[1];

  // inputs may arrive in dict order (w0,b0,w1,b1,w2,b2) or signature order (w0,w1,w2,b0,b1,b2)
  bool dict_order = (in_sizes[3] == 64);
  const float *w[3][3], *b[3][3];
  for (int g = 0; g < 3; ++g)
    for (int l = 0; l < 3; ++l) {
      int base = 2 + g * 6;
      int wi = dict_order ? (base + l * 2) : (base + l);
      int bi = dict_order ? (base + l * 2 + 1) : (base + 3 + l);
      w[g][l] = (const float*)d_in[wi];
      b[g][l] = (const float*)d_in[bi];
    }

  float* ws = (float*)d_ws;
  float* xx = ws;
  float* xy = xx + N_PTS;
  float* xz = xy + N_PTS;
  float* x1x = xz + N_PTS;
  float* x1y = x1x + NP1;
  float* x1z = x1y + NP1;
  float* x2x = x1z + NP1;
  float* x2y = x2x + NP2;
  float* x2z = x2y + NP2;
  int* gidx1 = (int*)(x2z + NP2);            // 2048*32
  int* gidx2 = gidx1 + NP1 * NSAMP1;         // 512*64
  float* f1 = (float*)(gidx2 + NP2 * NSAMP2);// 2048*128
  float* f2 = f1 + NP1 * 128;                // 512*256
  float* Xp = f2 + NP2 * 256;                // 8192*131 pool (also 8192*15, 512*259)
  float* Ha = Xp + 8192 * 131;               // 8192*128 pool
  float* Hb = Ha + 8192 * 128;               // 8192*128 pool
  float* Hc = Hb + 8192 * 128;               // 8192*256 pool (also 512*1024)

  const float R2A = (float)(0.4 * 0.4);  // f32 of python-f64 product: 1 ulp below 0.4f*0.4f
  const float R2B = (float)(0.8 * 0.8);

  k_prep<<<128, 256, 0, stream>>>(pts, prop, xx, xy, xz);
  k_fps1<<<1, F1T, 0, stream>>>(xx, xy, xz, x1x, x1y, x1z);
  k_fps2<<<1, F2T, 0, stream>>>(x1x, x1y, x1z, x2x, x2y, x2z);
  k_ballq<<<512, 256, 0, stream>>>(xx, xy, xz, N_PTS, x1x, x1y, x1z, NP1, R2A, NSAMP1, gidx1);
  k_ballq<<<128, 256, 0, stream>>>(x1x, x1y, x1z, NP1, x2x, x2y, x2z, NP2, R2B, NSAMP2, gidx2);

  // SA1: 65536 rows in 8 chunks of 8192 (s-chunks of 256)
  for (int ch = 0; ch < 8; ++ch) {
    int rbase = ch * 8192;
    k_gather1<<<32, 256, 0, stream>>>(pts, prop, xx, xy, xz, x1x, x1y, x1z, gidx1, Xp, rbase);
    k_gemm<<<dim3(1, 128), 256, 0, stream>>>(Xp, w[0][0], b[0][0], Ha, 8192, 64, 15);
    k_gemm<<<dim3(1, 128), 256, 0, stream>>>(Ha, w[0][1], b[0][1], Hb, 8192, 64, 64);
    k_gemm<<<dim3(2, 128), 256, 0, stream>>>(Hb, w[0][2], b[0][2], Hc, 8192, 128, 64);
    k_maxpool<<<128, 256, 0, stream>>>(Hc, f1, 256, 32, 128, ch * 256);
  }

  // SA2: 32768 rows in 4 chunks of 8192 (s-chunks of 128)
  for (int ch = 0; ch < 4; ++ch) {
    int rbase = ch * 8192;
    k_gather2<<<(8192 * 131 + 255) / 256, 256, 0, stream>>>(x1x, x1y, x1z, x2x, x2y, x2z,
                                                            gidx2, f1, Xp, rbase);
    k_gemm<<<dim3(2, 128), 256, 0, stream>>>(Xp, w[1][0], b[1][0], Ha, 8192, 128, 131);
    k_gemm<<<dim3(2, 128), 256, 0, stream>>>(Ha, w[1][1], b[1][1], Hb, 8192, 128, 128);
    k_gemm<<<dim3(4, 128), 256, 0, stream>>>(Hb, w[1][2], b[1][2], Hc, 8192, 256, 128);
    k_maxpool<<<128, 256, 0, stream>>>(Hc, f2, 128, 64, 256, ch * 128);
  }

  // SA3
  k_gather3<<<(512 * 259 + 255) / 256, 256, 0, stream>>>(x2x, x2y, x2z, f2, Xp);
  k_gemm<<<dim3(4, 8), 256, 0, stream>>>(Xp, w[2][0], b[2][0], Ha, 512, 256, 259);
  k_gemm<<<dim3(8, 8), 256, 0, stream>>>(Ha, w[2][1], b[2][1], Hb, 512, 512, 256);
  k_gemm<<<dim3(16, 8), 256, 0, stream>>>(Hb, w[2][2], b[2][2], Hc, 512, 1024, 512);
  k_maxpool<<<4, 256, 0, stream>>>(Hc, (float*)d_out, 1, 512, 1024, 0);
}

// Round 2
// 6240.525 us; speedup vs baseline: 1.4746x; 1.4746x over previous
//
#include <hip/hip_runtime.h>
#include <cstdint>
#include <cstddef>

typedef unsigned long long ull;

#define N_PTS  32768
#define NP1    2048
#define NSAMP1 32
#define NP2    512
#define NSAMP2 64

// ---------------- prep: xyz = points - [x,y,0], SoA ----------------
__global__ __launch_bounds__(256) void k_prep(const float* __restrict__ pts,
                                              const float* __restrict__ prop,
                                              float* __restrict__ xx,
                                              float* __restrict__ xy,
                                              float* __restrict__ xz) {
  int t = blockIdx.x * 256 + threadIdx.x;
  if (t >= N_PTS) return;
  float x = prop[0], y = prop[1];
  xx[t] = __fsub_rn(pts[3 * t + 0], x);
  xy[t] = __fsub_rn(pts[3 * t + 1], y);
  xz[t] = pts[3 * t + 2];
}

// ---------------- FPS1: 2048 of 32768, single persistent block ----------------
// 512 threads, 64 pts/thread. px/py/d + 33 z-slices in regs (225 VGPR), 31
// z-slices in LDS (63.5 KB). __launch_bounds__(512,2) -> 256-VGPR cap, no spill.
// Inner loop tracks max value only (10 VALU ops/pt); argmax index recovered by
// an exec-masked rescan in the (rare) waves holding the winner, then LDS
// atomicMin into a double-buffered winner slot (2 barriers/iter).
#define F1T 512
#define F1P 64
#define F1R 33                // z-coords kept in regs for s < F1R
#define F1L (F1P - F1R)       // 31 z-coord slices in LDS (31*512*4 = 63488 B)

__global__ __launch_bounds__(F1T, 2) void k_fps1(const float* __restrict__ xx,
                                                 const float* __restrict__ xy,
                                                 const float* __restrict__ xz,
                                                 float* __restrict__ ox,
                                                 float* __restrict__ oy,
                                                 float* __restrict__ oz) {
  __shared__ float pzl[F1L * F1T];
  __shared__ float wmax[F1T / 64];
  __shared__ int S[2];                      // double-buffered winner index
  int tid = threadIdx.x;
  float px[F1P], py[F1P], pzr[F1R], d[F1P];
#pragma unroll
  for (int s = 0; s < F1P; ++s) {
    int i = s * F1T + tid;                  // point-major: coalesced, LDS conflict-free
    px[s] = xx[i];
    py[s] = xy[i];
    float z = xz[i];
    if (s < F1R) pzr[s] = z;
    else pzl[(s - F1R) * F1T + tid] = z;
    d[s] = 1e10f;
  }
  if (tid == 0) { S[0] = 0; S[1] = 0x7fffffff; }
  __syncthreads();
  for (int it = 0; it < NP1; ++it) {
    int f = __builtin_amdgcn_readfirstlane(S[it & 1]);
    float cx = xx[f], cy = xy[f], cz = xz[f];
    if (tid == 0) { ox[it] = cx; oy[it] = cy; oz[it] = cz; }
    float bestv = -1.0f;
#pragma unroll
    for (int s = 0; s < F1P; ++s) {
      float z = (s < F1R) ? pzr[s] : pzl[(s - F1R) * F1T + tid];
      // exact reference arithmetic: no fma, (dx^2 + dy^2) + dz^2
      float dx = __fsub_rn(px[s], cx);
      float dy = __fsub_rn(py[s], cy);
      float dz = __fsub_rn(z, cz);
      float d2 = __fadd_rn(__fadd_rn(__fmul_rn(dx, dx), __fmul_rn(dy, dy)), __fmul_rn(dz, dz));
      float dn = fminf(d[s], d2);
      d[s] = dn;
      bestv = fmaxf(bestv, dn);
    }
    float wv = bestv;
#pragma unroll
    for (int m = 1; m < 64; m <<= 1) wv = fmaxf(wv, __shfl_xor(wv, m, 64));
    if ((tid & 63) == 0) wmax[tid >> 6] = wv;
    __syncthreads();                         // (A) wmax ready; all reads of S[it&1] done
    float gb = wmax[0];
#pragma unroll
    for (int k = 1; k < F1T / 64; ++k) gb = fmaxf(gb, wmax[k]);
    if (bestv == gb) {                       // only waves holding a global max pay the scan
      int cand = 0x7fffffff;
#pragma unroll
      for (int s = F1P - 1; s >= 0; --s) cand = (d[s] == gb) ? (s * F1T + tid) : cand;
      atomicMin(&S[(it + 1) & 1], cand);     // max value is a selection -> bitwise match exists
    }
    if (tid == 0) S[it & 1] = 0x7fffffff;    // reset: becomes dst at it+1
    __syncthreads();                         // (B) winner final
  }
}

// ---------------- FPS2: 512 of 2048, single block, 512 threads x 4 pts ----------------
#define F2T 512
#define F2P 4
__global__ __launch_bounds__(F2T, 2) void k_fps2(const float* __restrict__ x1x,
                                                 const float* __restrict__ x1y,
                                                 const float* __restrict__ x1z,
                                                 float* __restrict__ ox,
                                                 float* __restrict__ oy,
                                                 float* __restrict__ oz) {
  __shared__ float sx[NP1], sy[NP1], sz[NP1];   // 24 KB: centroid reads become LDS broadcast
  __shared__ float wmax[F2T / 64];
  __shared__ int S[2];
  int tid = threadIdx.x;
  float px[F2P], py[F2P], pz[F2P], d[F2P];
#pragma unroll
  for (int s = 0; s < F2P; ++s) {
    int i = s * F2T + tid;
    px[s] = x1x[i]; py[s] = x1y[i]; pz[s] = x1z[i];
    sx[i] = px[s];  sy[i] = py[s];  sz[i] = pz[s];
    d[s] = 1e10f;
  }
  if (tid == 0) { S[0] = 0; S[1] = 0x7fffffff; }
  __syncthreads();
  for (int it = 0; it < NP2; ++it) {
    int f = __builtin_amdgcn_readfirstlane(S[it & 1]);
    float cx = sx[f], cy = sy[f], cz = sz[f];  // LDS broadcast, ~120 cyc
    if (tid == 0) { ox[it] = cx; oy[it] = cy; oz[it] = cz; }
    float bestv = -1.0f;
#pragma unroll
    for (int s = 0; s < F2P; ++s) {
      float dx = __fsub_rn(px[s], cx);
      float dy = __fsub_rn(py[s], cy);
      float dz = __fsub_rn(pz[s], cz);
      float d2 = __fadd_rn(__fadd_rn(__fmul_rn(dx, dx), __fmul_rn(dy, dy)), __fmul_rn(dz, dz));
      float dn = fminf(d[s], d2);
      d[s] = dn;
      bestv = fmaxf(bestv, dn);
    }
    float wv = bestv;
#pragma unroll
    for (int m = 1; m < 64; m <<= 1) wv = fmaxf(wv, __shfl_xor(wv, m, 64));
    if ((tid & 63) == 0) wmax[tid >> 6] = wv;
    __syncthreads();                         // (A)
    float gb = wmax[0];
#pragma unroll
    for (int k = 1; k < F2T / 64; ++k) gb = fmaxf(gb, wmax[k]);
    if (bestv == gb) {
      int cand = 0x7fffffff;
#pragma unroll
      for (int s = F2P - 1; s >= 0; --s) cand = (d[s] == gb) ? (s * F2T + tid) : cand;
      atomicMin(&S[(it + 1) & 1], cand);
    }
    if (tid == 0) S[it & 1] = 0x7fffffff;
    __syncthreads();                         // (B)
  }
}

// ---------------- ball query: first ns indices (ascending) within r2, pad with first ----------------
__global__ void k_ballq(const float* __restrict__ px, const float* __restrict__ py,
                        const float* __restrict__ pz, int n,
                        const float* __restrict__ qx, const float* __restrict__ qy,
                        const float* __restrict__ qz, int S,
                        float r2, int ns, int* __restrict__ out) {
  int w = (blockIdx.x * (int)blockDim.x + threadIdx.x) >> 6;  // one wave per query
  int lane = threadIdx.x & 63;
  if (w >= S) return;
  float cx = qx[w], cy = qy[w], cz = qz[w];
  int found = 0, first = 0;
  bool havefirst = false;
  for (int base = 0; base < n && found < ns; base += 64) {
    int i = base + lane;
    float dx = __fsub_rn(px[i], cx);
    float dy = __fsub_rn(py[i], cy);
    float dz = __fsub_rn(pz[i], cz);
    float d2 = __fadd_rn(__fadd_rn(__fmul_rn(dx, dx), __fmul_rn(dy, dy)), __fmul_rn(dz, dz));
    bool isin = d2 <= r2;
    ull m = __ballot(isin);
    if (!havefirst && m != 0ull) { first = base + __builtin_ctzll(m); havefirst = true; }
    if (isin) {
      int r = (int)__popcll(m & ((1ull << lane) - 1ull));
      int slot = found + r;
      if (slot < ns) out[w * ns + slot] = i;
    }
    found += (int)__popcll(m);
  }
  for (int s2 = found + lane; s2 < ns; s2 += 64) out[w * ns + s2] = first;
}

// ---------------- gather SA1 input rows (15 ch) ----------------
__global__ __launch_bounds__(256) void k_gather1(const float* __restrict__ pts,
                                                 const float* __restrict__ prop,
                                                 const float* __restrict__ xx,
                                                 const float* __restrict__ xy,
                                                 const float* __restrict__ xz,
                                                 const float* __restrict__ x1x,
                                                 const float* __restrict__ x1y,
                                                 const float* __restrict__ x1z,
                                                 const int* __restrict__ gidx,
                                                 float* __restrict__ X, int rbase) {
  int rl = blockIdx.x * 256 + threadIdx.x;
  if (rl >= 8192) return;
  int r = rbase + rl;
  int s = r >> 5;
  int g = gidx[r];
  float x = prop[0], y = prop[1], wz = prop[3];
  float w2 = wz * 0.5f;  // == w/2 exactly
  float oxp = __fadd_rn(x, w2), oxm = __fsub_rn(x, w2);
  float oyp = __fadd_rn(y, w2), oym = __fsub_rn(y, w2);
  float gx = xx[g], gy = xy[g], gz = xz[g];
  float pxv = pts[3 * g + 0], pyv = pts[3 * g + 1];
  float* o = X + (size_t)rl * 15;
  o[0] = __fsub_rn(gx, x1x[s]);
  o[1] = __fsub_rn(gy, x1y[s]);
  o[2] = __fsub_rn(gz, x1z[s]);
  o[3] = __fsub_rn(pxv, oxp);  o[4]  = gy;                    o[5]  = gz;
  o[6] = __fsub_rn(pxv, oxm);  o[7]  = gy;                    o[8]  = gz;
  o[9] = gx;                   o[10] = __fsub_rn(pyv, oyp);   o[11] = gz;
  o[12] = gx;                  o[13] = __fsub_rn(pyv, oym);   o[14] = gz;
}

// ---------------- gather SA2 input rows (131 ch), element-parallel ----------------
__global__ __launch_bounds__(256) void k_gather2(const float* __restrict__ x1x,
                                                 const float* __restrict__ x1y,
                                                 const float* __restrict__ x1z,
                                                 const float* __restrict__ x2x,
                                                 const float* __restrict__ x2y,
                                                 const float* __restrict__ x2z,
                                                 const int* __restrict__ gidx,
                                                 const float* __restrict__ f1,
                                                 float* __restrict__ X, int rbase) {
  int e = blockIdx.x * 256 + threadIdx.x;
  if (e >= 8192 * 131) return;
  int rl = e / 131, c = e % 131;
  int r = rbase + rl;
  int s = r >> 6;
  int g = gidx[r];
  float v;
  if (c == 0)      v = __fsub_rn(x1x[g], x2x[s]);
  else if (c == 1) v = __fsub_rn(x1y[g], x2y[s]);
  else if (c == 2) v = __fsub_rn(x1z[g], x2z[s]);
  else             v = f1[(size_t)g * 128 + (c - 3)];
  X[e] = v;
}

// ---------------- gather SA3 input rows (259 ch) ----------------
__global__ __launch_bounds__(256) void k_gather3(const float* __restrict__ x2x,
                                                 const float* __restrict__ x2y,
                                                 const float* __restrict__ x2z,
                                                 const float* __restrict__ f2,
                                                 float* __restrict__ X) {
  int e = blockIdx.x * 256 + threadIdx.x;
  if (e >= 512 * 259) return;
  int rl = e / 259, c = e % 259;
  float v;
  if (c == 0)      v = x2x[rl];
  else if (c == 1) v = x2y[rl];
  else if (c == 2) v = x2z[rl];
  else             v = f2[(size_t)rl * 256 + (c - 3)];
  X[e] = v;
}

// ---------------- relu GEMM: C[m][n] = relu(bias[n] + sum_k A[m,k]*W[n,k]) ----------------
// 64x64 tile, 256 threads, 4x4 per thread, transposed LDS staging for b128 reads
__global__ __launch_bounds__(256) void k_gemm(const float* __restrict__ A,
                                              const float* __restrict__ W,
                                              const float* __restrict__ bias,
                                              float* __restrict__ C,
                                              int M, int N, int K) {
  __shared__ __align__(16) float As[16][68];
  __shared__ __align__(16) float Bs[16][68];
  int tid = threadIdx.x;
  int bn = blockIdx.x * 64, bm = blockIdx.y * 64;
  int tx = tid & 15, ty = tid >> 4;
  float acc[4][4] = {{0.f, 0.f, 0.f, 0.f}, {0.f, 0.f, 0.f, 0.f},
                     {0.f, 0.f, 0.f, 0.f}, {0.f, 0.f, 0.f, 0.f}};
  for (int k0 = 0; k0 < K; k0 += 16) {
#pragma unroll
    for (int e = 0; e < 4; ++e) {
      int flat = tid + e * 256;
      int rr = flat >> 4, cc = flat & 15;
      As[cc][rr] = (k0 + cc < K) ? A[(size_t)(bm + rr) * K + (k0 + cc)] : 0.0f;
      Bs[cc][rr] = (k0 + cc < K) ? W[(size_t)(bn + rr) * K + (k0 + cc)] : 0.0f;
    }
    __syncthreads();
#pragma unroll
    for (int kk = 0; kk < 16; ++kk) {
      const float4 a = *(const float4*)&As[kk][ty * 4];
      const float4 b = *(const float4*)&Bs[kk][tx * 4];
      float av[4] = {a.x, a.y, a.z, a.w};
      float bb[4] = {b.x, b.y, b.z, b.w};
#pragma unroll
      for (int i = 0; i < 4; ++i)
#pragma unroll
        for (int j = 0; j < 4; ++j)
          acc[i][j] = fmaf(av[i], bb[j], acc[i][j]);
    }
    __syncthreads();
  }
#pragma unroll
  for (int i = 0; i < 4; ++i) {
    int m = bm + ty * 4 + i;
    float4 o;
    o.x = fmaxf(acc[i][0] + bias[bn + tx * 4 + 0], 0.0f);
    o.y = fmaxf(acc[i][1] + bias[bn + tx * 4 + 1], 0.0f);
    o.z = fmaxf(acc[i][2] + bias[bn + tx * 4 + 2], 0.0f);
    o.w = fmaxf(acc[i][3] + bias[bn + tx * 4 + 3], 0.0f);
    *(float4*)&C[(size_t)m * N + bn + tx * 4] = o;
  }
}

// ---------------- maxpool over Ks consecutive rows ----------------
__global__ __launch_bounds__(256) void k_maxpool(const float* __restrict__ H,
                                                 float* __restrict__ F,
                                                 int S, int Ks, int Nch, int sbase) {
  int t = blockIdx.x * 256 + threadIdx.x;
  if (t >= S * Nch) return;
  int sl = t / Nch, n = t % Nch;
  const float* p = H + (size_t)sl * Ks * Nch + n;
  float m = p[0];
  for (int k = 1; k < Ks; ++k) m = fmaxf(m, p[(size_t)k * Nch]);
  F[(size_t)(sbase + sl) * Nch + n] = m;
}

// ---------------- host ----------------
extern "C" void kernel_launch(void* const* d_in, const int* in_sizes, int n_in,
                              void* d_out, int out_size, void* d_ws, size_t ws_size,
                              hipStream_t stream) {
  (void)n_in; (void)out_size; (void)ws_size;
  const float* pts = (const float*)d_in[0];
  const float* prop = (const float*)d_in[1];

  // inputs may arrive in dict order (w0,b0,w1,b1,w2,b2) or signature order (w0,w1,w2,b0,b1,b2)
  bool dict_order = (in_sizes[3] == 64);
  const float *w[3][3], *b[3][3];
  for (int g = 0; g < 3; ++g)
    for (int l = 0; l < 3; ++l) {
      int base = 2 + g * 6;
      int wi = dict_order ? (base + l * 2) : (base + l);
      int bi = dict_order ? (base + l * 2 + 1) : (base + 3 + l);
      w[g][l] = (const float*)d_in[wi];
      b[g][l] = (const float*)d_in[bi];
    }

  float* ws = (float*)d_ws;
  float* xx = ws;
  float* xy = xx + N_PTS;
  float* xz = xy + N_PTS;
  float* x1x = xz + N_PTS;
  float* x1y = x1x + NP1;
  float* x1z = x1y + NP1;
  float* x2x = x1z + NP1;
  float* x2y = x2x + NP2;
  float* x2z = x2y + NP2;
  int* gidx1 = (int*)(x2z + NP2);            // 2048*32
  int* gidx2 = gidx1 + NP1 * NSAMP1;         // 512*64
  float* f1 = (float*)(gidx2 + NP2 * NSAMP2);// 2048*128
  float* f2 = f1 + NP1 * 128;                // 512*256
  float* Xp = f2 + NP2 * 256;                // 8192*131 pool (also 8192*15, 512*259)
  float* Ha = Xp + 8192 * 131;               // 8192*128 pool
  float* Hb = Ha + 8192 * 128;               // 8192*128 pool
  float* Hc = Hb + 8192 * 128;               // 8192*256 pool (also 512*1024)

  const float R2A = (float)(0.4 * 0.4);  // f32 of python-f64 product: 1 ulp below 0.4f*0.4f
  const float R2B = (float)(0.8 * 0.8);

  k_prep<<<128, 256, 0, stream>>>(pts, prop, xx, xy, xz);
  k_fps1<<<1, F1T, 0, stream>>>(xx, xy, xz, x1x, x1y, x1z);
  k_fps2<<<1, F2T, 0, stream>>>(x1x, x1y, x1z, x2x, x2y, x2z);
  k_ballq<<<512, 256, 0, stream>>>(xx, xy, xz, N_PTS, x1x, x1y, x1z, NP1, R2A, NSAMP1, gidx1);
  k_ballq<<<128, 256, 0, stream>>>(x1x, x1y, x1z, NP1, x2x, x2y, x2z, NP2, R2B, NSAMP2, gidx2);

  // SA1: 65536 rows in 8 chunks of 8192 (s-chunks of 256)
  for (int ch = 0; ch < 8; ++ch) {
    int rbase = ch * 8192;
    k_gather1<<<32, 256, 0, stream>>>(pts, prop, xx, xy, xz, x1x, x1y, x1z, gidx1, Xp, rbase);
    k_gemm<<<dim3(1, 128), 256, 0, stream>>>(Xp, w[0][0], b[0][0], Ha, 8192, 64, 15);
    k_gemm<<<dim3(1, 128), 256, 0, stream>>>(Ha, w[0][1], b[0][1], Hb, 8192, 64, 64);
    k_gemm<<<dim3(2, 128), 256, 0, stream>>>(Hb, w[0][2], b[0][2], Hc, 8192, 128, 64);
    k_maxpool<<<128, 256, 0, stream>>>(Hc, f1, 256, 32, 128, ch * 256);
  }

  // SA2: 32768 rows in 4 chunks of 8192 (s-chunks of 128)
  for (int ch = 0; ch < 4; ++ch) {
    int rbase = ch * 8192;
    k_gather2<<<(8192 * 131 + 255) / 256, 256, 0, stream>>>(x1x, x1y, x1z, x2x, x2y, x2z,
                                                            gidx2, f1, Xp, rbase);
    k_gemm<<<dim3(2, 128), 256, 0, stream>>>(Xp, w[1][0], b[1][0], Ha, 8192, 128, 131);
    k_gemm<<<dim3(2, 128), 256, 0, stream>>>(Ha, w[1][1], b[1][1], Hb, 8192, 128, 128);
    k_gemm<<<dim3(4, 128), 256, 0, stream>>>(Hb, w[1][2], b[1][2], Hc, 8192, 256, 128);
    k_maxpool<<<128, 256, 0, stream>>>(Hc, f2, 128, 64, 256, ch * 128);
  }

  // SA3
  k_gather3<<<(512 * 259 + 255) / 256, 256, 0, stream>>>(x2x, x2y, x2z, f2, Xp);
  k_gemm<<<dim3(4, 8), 256, 0, stream>>>(Xp, w[2][0], b[2][0], Ha, 512, 256, 259);
  k_gemm<<<dim3(8, 8), 256, 0, stream>>>(Ha, w[2][1], b[2][1], Hb, 512, 512, 256);
  k_gemm<<<dim3(16, 8), 256, 0, stream>>>(Hb, w[2][2], b[2][2], Hc, 512, 1024, 512);
  k_maxpool<<<4, 256, 0, stream>>>(Hc, (float*)d_out, 1, 512, 1024, 0);
}